// Round 11
// baseline (4267.826 us; speedup 1.0000x reference)
//
#include <hip/hip_runtime.h>

#define NSEG 63

typedef float    f32x4  __attribute__((ext_vector_type(4)));
typedef _Float16 half8  __attribute__((ext_vector_type(8)));
typedef _Float16 half4v __attribute__((ext_vector_type(4)));

#define W2_ELEMS 524288
#define W1_ELEMS 16384
#define W1H_OFF (2*W2_ELEMS)
#define W1L_OFF (W1H_OFF + W1_ELEMS)
#define B2_OFF  (W1L_OFF + W1_ELEMS)

__device__ __forceinline__ float fast_tanh(float x){
  float e = __builtin_amdgcn_exp2f(x * 2.885390081777927f); // 2*log2(e)
  float r = __builtin_amdgcn_rcpf(e + 1.0f);
  return fmaf(-2.0f, r, 1.0f);
}

__device__ __forceinline__ f32x4 sp4(float v){ f32x4 o = {v,v,v,v}; return o; }

// async global->LDS DMA, 16B per lane: lane i writes lds_base + i*16
__device__ __forceinline__ void dma16(const _Float16* g, _Float16* l){
  __builtin_amdgcn_global_load_lds(
      (const __attribute__((address_space(1))) unsigned int*)g,
      (__attribute__((address_space(3))) unsigned int*)l,
      16, 0, 0);
}

// W2 ws layout (same as R10): per (kt,i,hg) 512-half block, k-subgroup rotated
// so contiguous DMA lands bank-conflict-free for the MFMA B-frag reader.
__global__ __launch_bounds__(256) void prep_kernel(const float* __restrict__ W1,
                                                   const float* __restrict__ W2,
                                                   const float* __restrict__ b2,
                                                   _Float16* __restrict__ ws){
  int idx = blockIdx.x*256 + threadIdx.x;
  if (idx < W2_ELEMS){
    int m = idx >> 12, col = idx & 4095;       // W2[m][col], col = h*32+i
    int h = col >> 5,  i = col & 31;
    int kt = m >> 5,   kk = m & 31;
    float w = W2[idx];
    _Float16 hi = (_Float16)w;                 // fp16-hi only
    int hg = h >> 4, n = h & 15;
    int kq = kk >> 3, kl = kk & 7;
    int pos = kt*131072 + i*4096 + hg*512
            + n*32 + (((kq + (n>>1)) & 3) << 3) + kl;
    ws[pos] = hi;
  } else if (idx < W2_ELEMS + W1_ELEMS){
    int j = idx - W2_ELEMS;
    int m = j >> 7, n = j & 127;               // W1[m][n]
    float w = W1[j];
    _Float16 hi = (_Float16)w;
    _Float16 lo = (_Float16)(w - (float)hi);
    int pos = ((m>>5)*128 + n)*32 + (m&31);
    ws[W1H_OFF + pos] = hi;
    ws[W1L_OFF + pos] = lo;
  } else if (idx < W2_ELEMS + W1_ELEMS + 4096){
    int j = idx - (W2_ELEMS + W1_ELEMS);       // b2[h*32+i]
    float* b2p = (float*)(ws + B2_OFF);
    b2p[(j & 31)*128 + (j >> 5)] = b2[j];
  }
}

// 64 WGs x 512 threads x 32 rows (two 16-row M-tiles per wave). W2 streamed
// via async global_load_lds into 3 rotating per-wave LDS buffers, each W2
// fragment feeds both M-tiles. H-lo plane dropped (register budget).
// zfb/ylds alias the W2L region (only used outside the scan).
__global__ __launch_bounds__(512) void cde_kernel(
    const float* __restrict__ coeffs,
    const float* __restrict__ W_init, const float* __restrict__ b_init,
    const float* __restrict__ b1,
    const float* __restrict__ W_ro,  const float* __restrict__ b_ro,
    const float* __restrict__ We1,   const float* __restrict__ be1,
    const float* __restrict__ We2,   const float* __restrict__ be2,
    const _Float16* __restrict__ wsw,
    float* __restrict__ out)
{
  __shared__ __align__(16) _Float16 W2L[3][8][4][512]; // 96KB; aliased by head
  __shared__ __align__(16) _Float16 Zs[32][136];  // stage-z hi (A of GEMM1)
  __shared__ __align__(16) _Float16 Zl[32][136];  // stage-z lo
  __shared__ __align__(16) _Float16 Hs[32][136];  // H fp16 (A of GEMM2)
  __shared__ __align__(16) float dXT[3][32][32];  // dX variants [var][i][row]
  __shared__ __align__(16) float b2L[4096];       // permuted b2; evolve tmp later

  const int tid  = threadIdx.x;
  const int wave = tid >> 6;          // 0..7
  const int lane = tid & 63;
  const int q    = lane >> 4;
  const int ln16 = lane & 15;
  const int row4 = q * 4;
  const int bg   = blockIdx.x * 32;
  const int n0   = wave * 16;
  const int fo   = ln16*32 + (((q + (ln16>>1)) & 3) << 3);

  float* zfb  = (float*)&W2L[0][0][0][0];   // [32][128], 16KB (alias)
  float* ylds = zfb + 4096;                 // [32][32], 4KB (alias)

  // ---- stage b2p into LDS ----
  {
    const float* b2p = (const float*)(wsw + B2_OFF);
    #pragma unroll
    for (int j = 0; j < 8; ++j) b2L[tid + j*512] = b2p[tid + j*512];
  }
  // ---- stage X0 = a[:,0] into dXT[0][i][r], 1024 entries ----
  #pragma unroll
  for (int j = 0; j < 2; ++j){
    int idx = tid + j*512;
    int r = idx >> 5, i = idx & 31;
    dXT[0][i][r] = coeffs[(size_t)(bg + r)*(NSEG*128) + i];
  }
  __syncthreads();

  // ---- z0 = X0 @ W_init + b_init (fp32) -> zfb + Zs/Zl ----
  #pragma unroll
  for (int j = 0; j < 2; ++j){
    int idx = tid + j*512;
    int r = idx >> 5, h0 = (idx & 31) * 4;
    f32x4 acc = *(const f32x4*)&b_init[h0];
    #pragma unroll 8
    for (int i = 0; i < 32; ++i)
      acc += sp4(dXT[0][i][r]) * (*(const f32x4*)&W_init[i*128 + h0]);
    *(f32x4*)&zfb[r*128 + h0] = acc;
    half4v zh, zl;
    #pragma unroll
    for (int k = 0; k < 4; ++k){
      _Float16 hi = (_Float16)acc[k];
      zh[k] = hi; zl[k] = (_Float16)(acc[k] - (float)hi);
    }
    *(half4v*)&Zs[r][h0] = zh;
    *(half4v*)&Zl[r][h0] = zl;
  }

  // per-wave W1 fragments (persist in regs)
  half8 w1h[4], w1l[4];
  {
    const half8* W1h8 = (const half8*)(wsw + W1H_OFF);
    const half8* W1l8 = (const half8*)(wsw + W1L_OFF);
    #pragma unroll
    for (int kt = 0; kt < 4; ++kt){
      int fi = (kt*128 + n0 + ln16)*4 + q;
      w1h[kt] = W1h8[fi];
      w1l[kt] = W1l8[fi];
    }
  }
  const float b1v = b1[n0 + ln16];
  __syncthreads();

  // ---- register z-state for both owned fragments ----
  f32x4 zbA, zbB, zaA = sp4(0.0f), zaB = sp4(0.0f);
  #pragma unroll
  for (int k = 0; k < 4; ++k){
    zbA[k] = zfb[(row4 + k)*128 + n0 + ln16];
    zbB[k] = zfb[(16 + row4 + k)*128 + n0 + ln16];
  }
  __syncthreads();   // all zfb reads done before DMA overwrites W2L region

  // DMA one i-chunk (this wave's n-slice, 4 kt x 1KB) into buffer b
  auto issue = [&](int i, int b){
    const _Float16* g = wsw + (i*128 + n0)*32 + lane*8;
    _Float16* l = &W2L[b][wave][0][0];
    #pragma unroll
    for (int kt = 0; kt < 4; ++kt)
      dma16(g + kt*131072, l + kt*512);
  };

  // ================= CDE RK4 scan =================
  for (int t = 0; t < NSEG; ++t){
    // stage dX variants
    #pragma unroll
    for (int j = 0; j < 2; ++j){
      int idx = tid + j*512;
      int r = idx >> 5, i = idx & 31;
      const float* base = coeffs + (size_t)(bg + r)*(NSEG*128) + (size_t)t*128;
      float bb = base[32+i], cc = base[64+i], dd = base[96+i];
      dXT[0][i][r] = bb;
      dXT[1][i][r] = bb + cc + 0.75f*dd;
      float d4;
      if (t < NSEG-1) d4 = base[128+32+i];
      else            d4 = bb + 2.0f*cc + 3.0f*dd;
      dXT[2][i][r] = d4;
    }

    #pragma unroll 1
    for (int s = 0; s < 4; ++s){
      // prologue: start DMA of chunks 0..2 (latency covered by Phase A)
      issue(0, 0); issue(1, 1); issue(2, 2);

      // ---- Phase A: GEMM1 per M-tile: H = relu(Z @ W1 + b1), Z split ----
      auto gemm1 = [&](int ro){
        half8 a1h[4], a1l[4];
        #pragma unroll
        for (int kt = 0; kt < 4; ++kt){
          a1h[kt] = *(const half8*)&Zs[ro + ln16][kt*32 + q*8];
          a1l[kt] = *(const half8*)&Zl[ro + ln16][kt*32 + q*8];
        }
        f32x4 u0 = sp4(b1v), u1 = sp4(0.0f), u2 = sp4(0.0f);
        #pragma unroll
        for (int kt = 0; kt < 4; ++kt){
          u0 = __builtin_amdgcn_mfma_f32_16x16x32_f16(a1h[kt], w1h[kt], u0, 0, 0, 0);
          u1 = __builtin_amdgcn_mfma_f32_16x16x32_f16(a1l[kt], w1h[kt], u1, 0, 0, 0);
          u2 = __builtin_amdgcn_mfma_f32_16x16x32_f16(a1h[kt], w1l[kt], u2, 0, 0, 0);
        }
        #pragma unroll
        for (int r = 0; r < 4; ++r){
          float hv = u0[r] + u1[r] + u2[r];
          hv = hv > 0.0f ? hv : 0.0f;
          Hs[ro + row4 + r][n0 + ln16] = (_Float16)hv;
        }
      };
      gemm1(0);
      gemm1(16);
      __syncthreads();

      // ---- Phase B: GEMM2 + tanh + dX, LDS-DMA pipelined W2, 2 M-tiles ----
      half8 a2hA[4], a2hB[4];
      #pragma unroll
      for (int kt = 0; kt < 4; ++kt){
        a2hA[kt] = *(const half8*)&Hs[ln16][kt*32 + q*8];
        a2hB[kt] = *(const half8*)&Hs[16 + ln16][kt*32 + q*8];
      }
      const int v = (s == 0) ? 0 : ((s == 3) ? 2 : 1);
      f32x4 dzA = sp4(0.0f), dzB = sp4(0.0f);

      auto body = [&](const _Float16* Wb, int i){
        float b2v = b2L[i*128 + n0 + ln16];
        half8 bf0 = *(const half8*)(Wb + fo);
        half8 bf1 = *(const half8*)(Wb +  512 + fo);
        half8 bf2 = *(const half8*)(Wb + 1024 + fo);
        half8 bf3 = *(const half8*)(Wb + 1536 + fo);
        f32x4 uA = sp4(b2v), uB = sp4(b2v);
        uA = __builtin_amdgcn_mfma_f32_16x16x32_f16(a2hA[0], bf0, uA, 0, 0, 0);
        uB = __builtin_amdgcn_mfma_f32_16x16x32_f16(a2hB[0], bf0, uB, 0, 0, 0);
        uA = __builtin_amdgcn_mfma_f32_16x16x32_f16(a2hA[1], bf1, uA, 0, 0, 0);
        uB = __builtin_amdgcn_mfma_f32_16x16x32_f16(a2hB[1], bf1, uB, 0, 0, 0);
        uA = __builtin_amdgcn_mfma_f32_16x16x32_f16(a2hA[2], bf2, uA, 0, 0, 0);
        uB = __builtin_amdgcn_mfma_f32_16x16x32_f16(a2hB[2], bf2, uB, 0, 0, 0);
        uA = __builtin_amdgcn_mfma_f32_16x16x32_f16(a2hA[3], bf3, uA, 0, 0, 0);
        uB = __builtin_amdgcn_mfma_f32_16x16x32_f16(a2hB[3], bf3, uB, 0, 0, 0);
        f32x4 dxvA = *(const f32x4*)&dXT[v][i][row4];
        f32x4 dxvB = *(const f32x4*)&dXT[v][i][16 + row4];
        #pragma unroll
        for (int r = 0; r < 4; ++r){
          dzA[r] = fmaf(fast_tanh(uA[r]), dxvA[r], dzA[r]);
          dzB[r] = fmaf(fast_tanh(uB[r]), dxvB[r], dzB[r]);
        }
      };

      {
        int b = 0;
        #pragma unroll 1
        for (int i = 0; i < 30; ++i){
          asm volatile("s_waitcnt vmcnt(8)" ::: "memory");
          body(&W2L[b][wave][0][0], i);
          if (i <= 28) issue(i + 3, b);       // (i+3)%3 == i%3 == b
          b = (b == 2) ? 0 : b + 1;
        }
        asm volatile("s_waitcnt vmcnt(4)" ::: "memory");
        body(&W2L[0][wave][0][0], 30);        // 30 % 3 == 0
        asm volatile("s_waitcnt vmcnt(0)" ::: "memory");
        body(&W2L[1][wave][0][0], 31);        // 31 % 3 == 1
      }

      // ---- in-register RK4 update + Zs/Zl write, both tiles ----
      const float wk = (s == 3) ? 1.0f : 2.0f;
      #pragma unroll
      for (int k = 0; k < 4; ++k){
        // tile A
        float zanA = (s == 0) ? dzA[k] : zaA[k] + wk*dzA[k];
        zaA[k] = zanA;
        float zsA;
        if (s == 3){ zbA[k] += zanA*(1.0f/6.0f); zsA = zbA[k]; }
        else if (s == 2) zsA = zbA[k] + dzA[k];
        else             zsA = zbA[k] + 0.5f*dzA[k];
        _Float16 hiA = (_Float16)zsA;
        Zs[row4 + k][n0 + ln16] = hiA;
        Zl[row4 + k][n0 + ln16] = (_Float16)(zsA - (float)hiA);
        // tile B
        float zanB = (s == 0) ? dzB[k] : zaB[k] + wk*dzB[k];
        zaB[k] = zanB;
        float zsB;
        if (s == 3){ zbB[k] += zanB*(1.0f/6.0f); zsB = zbB[k]; }
        else if (s == 2) zsB = zbB[k] + dzB[k];
        else             zsB = zbB[k] + 0.5f*dzB[k];
        _Float16 hiB = (_Float16)zsB;
        Zs[16 + row4 + k][n0 + ln16] = hiB;
        Zl[16 + row4 + k][n0 + ln16] = (_Float16)(zsB - (float)hiB);
      }
      __syncthreads();
    }
  }

  // ---- write final z back to zfb (W2L region; all DMAs drained) ----
  #pragma unroll
  for (int k = 0; k < 4; ++k){
    zfb[(row4 + k)*128 + n0 + ln16]      = zbA[k];
    zfb[(16 + row4 + k)*128 + n0 + ln16] = zbB[k];
  }
  __syncthreads();

  // ================= readout + evolve head (fp32), 2 rows/thread ==========
  float yb[2], yac[2] = {0.0f, 0.0f};
  #pragma unroll
  for (int j = 0; j < 2; ++j){
    int idx = tid + j*512;
    int r = idx >> 5, c = idx & 31;
    float yv = b_ro[c];
    #pragma unroll 8
    for (int h = 0; h < 128; ++h)
      yv = fmaf(zfb[r*128 + h], W_ro[h*32 + c], yv);
    ylds[r*32 + c] = yv;
    yb[j] = yv;
  }
  __syncthreads();

  for (int st = 0; st < 10; ++st){
    #pragma unroll 1
    for (int s = 0; s < 4; ++s){
      // tmp = tanh(ys @ We1 + be1) -> b2L (reused as [32][128])
      #pragma unroll
      for (int j = 0; j < 2; ++j){
        int idx = tid + j*512;
        int rr = idx >> 5, m0 = (idx & 31) * 4;
        f32x4 acc = *(const f32x4*)&be1[m0];
        #pragma unroll 4
        for (int i = 0; i < 32; ++i)
          acc += sp4(ylds[rr*32 + i]) * (*(const f32x4*)&We1[i*128 + m0]);
        f32x4 tt;
        tt.x = fast_tanh(acc.x); tt.y = fast_tanh(acc.y);
        tt.z = fast_tanh(acc.z); tt.w = fast_tanh(acc.w);
        *(f32x4*)&b2L[rr*128 + m0] = tt;
      }
      __syncthreads();
      #pragma unroll
      for (int j = 0; j < 2; ++j){
        int idx = tid + j*512;
        int r = idx >> 5, c = idx & 31;
        float kv = be2[c];
        #pragma unroll 8
        for (int m = 0; m < 128; ++m)
          kv = fmaf(b2L[r*128 + m], We2[m*32 + c], kv);
        float ysn;
        if      (s == 0){ yac[j] = kv;        ysn = yb[j] + 0.25f*kv; }
        else if (s == 1){ yac[j] += 2.0f*kv;  ysn = yb[j] + 0.25f*kv; }
        else if (s == 2){ yac[j] += 2.0f*kv;  ysn = yb[j] + 0.5f*kv;  }
        else            { yac[j] += kv;       yb[j] += yac[j]*(1.0f/12.0f); ysn = yb[j]; }
        ylds[r*32 + c] = ysn;
      }
      __syncthreads();
    }
  }
  #pragma unroll
  for (int j = 0; j < 2; ++j){
    int idx = tid + j*512;
    int r = idx >> 5, c = idx & 31;
    out[(size_t)(bg + r)*32 + c] = yb[j];
  }
}

extern "C" void kernel_launch(void* const* d_in, const int* in_sizes, int n_in,
                              void* d_out, int out_size, void* d_ws, size_t ws_size,
                              hipStream_t stream){
  const float* coeffs = (const float*)d_in[0];
  const float* W_init = (const float*)d_in[1];
  const float* b_init = (const float*)d_in[2];
  const float* W1     = (const float*)d_in[3];
  const float* b1     = (const float*)d_in[4];
  const float* W2     = (const float*)d_in[5];
  const float* b2     = (const float*)d_in[6];
  const float* W_ro   = (const float*)d_in[7];
  const float* b_ro   = (const float*)d_in[8];
  const float* We1    = (const float*)d_in[9];
  const float* be1    = (const float*)d_in[10];
  const float* We2    = (const float*)d_in[11];
  const float* be2    = (const float*)d_in[12];
  _Float16* ws        = (_Float16*)d_ws;

  prep_kernel<<<2128, 256, 0, stream>>>(W1, W2, b2, ws);
  cde_kernel<<<64, 512, 0, stream>>>(coeffs, W_init, b_init, b1, W_ro, b_ro,
                                     We1, be1, We2, be2, ws, (float*)d_out);
}